// Round 12
// baseline (2804.782 us; speedup 1.0000x reference)
//
#include <hip/hip_runtime.h>
#include <math.h>

#define B 128
#define S 2048
#define V 800
#define E 128
#define H 64
#define NL 3
#define M (B*S)

typedef unsigned short ushort_t;

__device__ __forceinline__ float bf2f(unsigned short u){
  return __uint_as_float(((unsigned int)u) << 16);
}
__device__ __forceinline__ unsigned short f2bf(float f){
  unsigned int u = __float_as_uint(f);
  u += 0x7fff + ((u >> 16) & 1);          // round-to-nearest-even
  return (unsigned short)(u >> 16);
}
__device__ __forceinline__ float fast_tanh(float x){
  float e = __expf(2.f*x);
  return 1.f - 2.f*__builtin_amdgcn_rcpf(e+1.f);
}
__device__ __forceinline__ int clamp_t(int t){
  return t < 0 ? 0 : (t > S-1 ? S-1 : t);
}

// ---- all-VALU 8x8 butterfly matvec (R11-proven) ---------------------------
// Lane l owns h[l]. Rows per lane: l ^ G(k), G(k) = (k&3)|((k&4)<<2).
// Cols: preserve bits{0,1,4}; spread bits{2,3} (rot4 orbit) + bit5
// (permlane32 pair). Folds xor1/xor2 (quad_perm DPP) + xor16 (permlane16
// pair). Runtime calibration absorbs permlane pairing conventions.
// NEW this round: TWO independent chains (fwd+bwd of one batch) per wave —
// chain A's tanh/fold stalls fill with chain B's fma stream. Per-chain state
// is only w[64]+~20 transients -> both fit ~200 VGPRs (R5's spill trap was
// the 128-reg LDS c-buffers, gone since R9).
#define DPP_XOR1 0xB1    // quad_perm [1,0,3,2]
#define DPP_XOR2 0x4E    // quad_perm [2,3,0,1]
#define DPP_ROR4  0x124  // row_ror:4
#define DPP_ROR8  0x128  // row_ror:8
#define DPP_ROR12 0x12C  // row_ror:12
#define DPPI(v, ctrl) __builtin_amdgcn_update_dpp(0, (v), (ctrl), 0xf, 0xf, false)
#define DPPF(v, ctrl) __int_as_float(DPPI(__float_as_int(v), (ctrl)))
__device__ __forceinline__ float bperm(int addr, float v){
  return __int_as_float(__builtin_amdgcn_ds_bpermute(addr, __float_as_int(v)));
}
__device__ __host__ __forceinline__ constexpr int Gmask(int k){
  return (k & 3) | ((k & 4) << 2);      // {0,1,2,3,16,17,18,19}
}

#if __has_builtin(__builtin_amdgcn_permlane32_swap)
#define HAVE_PL32 1
#else
#define HAVE_PL32 0
#endif
#if __has_builtin(__builtin_amdgcn_permlane16_swap)
#define HAVE_PL16 1
#else
#define HAVE_PL16 0
#endif

#if HAVE_PL32
#define XOR32F(x) ({ auto r_ = __builtin_amdgcn_permlane32_swap(__float_as_uint(x), __float_as_uint(x), false, false); \
                     __uint_as_float(pick32 ? r_[0] : r_[1]); })
#else
#define XOR32F(x) bperm(ba32, (x))
#endif
#if HAVE_PL16
#define XOR16F(x) ({ auto r_ = __builtin_amdgcn_permlane16_swap(__float_as_uint(x), __float_as_uint(x), false, false); \
                     __uint_as_float(pick16 ? r_[0] : r_[1]); })
#else
#define XOR16F(x) bperm(ba16, (x))
#endif

// Calibration: fills pick16, pick32, cm[8] (true source lane of gather op j).
#define CALIB() do {                                                         \
  int mk_ = i;                                                               \
  int g32m_;                                                                 \
  if (HAVE_PL32) {                                                           \
    auto r_ = __builtin_amdgcn_permlane32_swap((unsigned)mk_, (unsigned)mk_, false, false); \
    pick32 = ((int)r_[0] == (mk_ ^ 32));                                     \
    g32m_ = pick32 ? (int)r_[0] : (int)r_[1];                                \
  } else {                                                                   \
    g32m_ = mk_ ^ 32;                                                        \
  }                                                                          \
  if (HAVE_PL16) {                                                           \
    auto r_ = __builtin_amdgcn_permlane16_swap((unsigned)mk_, (unsigned)mk_, false, false); \
    pick16 = ((int)r_[0] == (mk_ ^ 16));                                     \
  }                                                                          \
  cm[0]=mk_;   cm[1]=DPPI(mk_,DPP_ROR4);                                     \
  cm[2]=DPPI(mk_,DPP_ROR8);  cm[3]=DPPI(mk_,DPP_ROR12);                      \
  cm[4]=g32m_; cm[5]=DPPI(g32m_,DPP_ROR4);                                   \
  cm[6]=DPPI(g32m_,DPP_ROR8); cm[7]=DPPI(g32m_,DPP_ROR12);                   \
} while(0)

// W-tile load for one chain (uses cm from CALIB)
#define LOAD_W8(wreg, wbase) do {                                            \
  _Pragma("unroll")                                                          \
  for (int k=0;k<8;++k)                                                      \
    _Pragma("unroll")                                                        \
    for (int j=0;j<8;++j)                                                    \
      wreg[k*8+j] = (wbase)[(size_t)(i ^ Gmask(k))*H + cm[j]];               \
} while(0)

// 8 fmas (one gathered h value against one W-tile column), 8 indep chains
#define DOTJX(wX, jj, hvj)                                                   \
  p0_=fmaf(wX[0*8+jj],hvj,p0_); p1_=fmaf(wX[1*8+jj],hvj,p1_);                \
  p2_=fmaf(wX[2*8+jj],hvj,p2_); p3_=fmaf(wX[3*8+jj],hvj,p3_);                \
  p4_=fmaf(wX[4*8+jj],hvj,p4_); p5_=fmaf(wX[5*8+jj],hvj,p5_);                \
  p6_=fmaf(wX[6*8+jj],hvj,p6_); p7_=fmaf(wX[7*8+jj],hvj,p7_);

// one recurrence step for chain X (parameterized h and W registers)
#define BSTEPX(hX, wX, acc_expr)                                             \
  {                                                                          \
    float hv0_ = hX;                                                         \
    float hv1_ = DPPF(hX, DPP_ROR4);                                         \
    float hv2_ = DPPF(hX, DPP_ROR8);                                         \
    float hv3_ = DPPF(hX, DPP_ROR12);                                        \
    float g_  = XOR32F(hX);                                                  \
    float hv4_ = g_;                                                         \
    float hv5_ = DPPF(g_, DPP_ROR4);                                         \
    float hv6_ = DPPF(g_, DPP_ROR8);                                         \
    float hv7_ = DPPF(g_, DPP_ROR12);                                        \
    float p0_=(acc_expr), p1_=0.f,p2_=0.f,p3_=0.f,p4_=0.f,p5_=0.f,p6_=0.f,p7_=0.f; \
    DOTJX(wX,0,hv0_); DOTJX(wX,1,hv1_); DOTJX(wX,2,hv2_); DOTJX(wX,3,hv3_);  \
    DOTJX(wX,4,hv4_); DOTJX(wX,5,hv5_); DOTJX(wX,6,hv6_); DOTJX(wX,7,hv7_);  \
    p0_ += DPPF(p1_, DPP_XOR1); p2_ += DPPF(p3_, DPP_XOR1);                  \
    p4_ += DPPF(p5_, DPP_XOR1); p6_ += DPPF(p7_, DPP_XOR1);                  \
    p0_ += DPPF(p2_, DPP_XOR2); p4_ += DPPF(p6_, DPP_XOR2);                  \
    p0_ += XOR16F(p4_);                                                      \
    hX = fast_tanh(p0_);                                                     \
  }
// ---------------------------------------------------------------------------

// pre_emb[v][n] = emb[v]·w_ih[0,n,:] + b_ih[0,n] + b_hh[0,n],  n = d*64+i
__global__ __launch_bounds__(128) void k_pre_emb(const float* __restrict__ emb,
    const float* __restrict__ w_ih, const float* __restrict__ b_ih, const float* __restrict__ b_hh,
    float* __restrict__ pe)
{
  const int v = blockIdx.x;
  const int n = threadIdx.x;           // 0..127
  const float* er = emb + (size_t)v*E;
  const float* wr = w_ih + (size_t)n*E;   // layer 0 rows
  float acc = b_ih[n] + b_hh[n];
  #pragma unroll
  for (int e=0;e<E;e+=4){
    float4 ev = *(const float4*)(er+e);
    float4 wv = *(const float4*)(wr+e);
    acc = fmaf(ev.x, wv.x, acc);
    acc = fmaf(ev.y, wv.y, acc);
    acc = fmaf(ev.z, wv.z, acc);
    acc = fmaf(ev.w, wv.w, acc);
  }
  pe[(size_t)v*128 + n] = acc;
}

// partial mean/max pools over S-chunks
__global__ __launch_bounds__(128) void k_pool(const int* __restrict__ x, const float* __restrict__ emb,
      float* __restrict__ psum, float* __restrict__ pmax)
{
  const int b = blockIdx.x, c = blockIdx.y, e = threadIdx.x;
  const int* xb = x + (size_t)b*S + c*(S/16);
  float s=0.f, m=-INFINITY;
  for (int k=0;k<S/16;++k){
    int v = xb[k];
    float val = emb[(size_t)v*E + e];
    s += val; m = fmaxf(m,val);
  }
  psum[((size_t)b*16 + c)*E + e] = s;
  pmax[((size_t)b*16 + c)*E + e] = m;
}

// layer-0 recurrence: BOTH directions of one batch in one wave (dual-chain),
// fused gather from L2-hot pe table (409 KB). ~200 VGPRs, no spill expected.
__global__ __attribute__((amdgpu_flat_work_group_size(64,64)))
__attribute__((amdgpu_waves_per_eu(1,1)))
void k_rec0(const int* __restrict__ x,
            const float* __restrict__ pe,
            ushort_t* __restrict__ y,
            const float* __restrict__ w_hh,
            float* __restrict__ hfin)
{
  const int b = blockIdx.x;           // 0..127
  const int i = threadIdx.x;          // 0..63
  bool pick16=false, pick32=false;
  int cm[8];
  const int ba32 = (i^32)<<2, ba16 = (i^16)<<2;
  (void)ba32; (void)ba16;
  CALIB();
  float wA[64], wB[64];
  LOAD_W8(wA, w_hh + (size_t)0*H*H);       // layer 0, d=0
  LOAD_W8(wB, w_hh + (size_t)1*H*H);       // layer 0, d=1
  const int* xb = x + (size_t)b*S;
  const float* peA = pe + i;               // d=0 half of pe row
  const float* peB = pe + 64 + i;          // d=1 half
  ushort_t* yA = y + (size_t)b*S*128 + i;
  ushort_t* yB = y + (size_t)b*S*128 + 64 + i;
  int tA = 0, tB = S-1;

  int vxA[8], vxB[8];
  #pragma unroll
  for (int k=0;k<8;++k){ vxA[k] = xb[k]; vxB[k] = xb[S-1-k]; }
  float plA[4], plB[4];
  #pragma unroll
  for (int k=0;k<4;++k){
    plA[k] = peA[(size_t)vxA[k]*128];
    plB[k] = peB[(size_t)vxB[k]*128];
  }
  float hA = 0.f, hB = 0.f;

#define STEP0A(r) do {                                                       \
    float acc = plA[(r)&3];                                                  \
    plA[(r)&3] = peA[(size_t)vxA[((r)+4)&7]*128];                            \
    vxA[(r)&7] = xb[clamp_t(tA + 8)];                                        \
    BSTEPX(hA, wA, acc);                                                     \
    yA[(size_t)tA*128] = f2bf(hA);                                           \
    tA += 1;                                                                 \
  } while(0)
#define STEP0B(r) do {                                                       \
    float acc = plB[(r)&3];                                                  \
    plB[(r)&3] = peB[(size_t)vxB[((r)+4)&7]*128];                            \
    vxB[(r)&7] = xb[clamp_t(tB - 8)];                                        \
    BSTEPX(hB, wB, acc);                                                     \
    yB[(size_t)tB*128] = f2bf(hB);                                           \
    tB -= 1;                                                                 \
  } while(0)

  for (int tq=0; tq<S; tq+=8){
    STEP0A(0); STEP0B(0);
    STEP0A(1); STEP0B(1);
    STEP0A(2); STEP0B(2);
    STEP0A(3); STEP0B(3);
    STEP0A(4); STEP0B(4);
    STEP0A(5); STEP0B(5);
    STEP0A(6); STEP0B(6);
    STEP0A(7); STEP0B(7);
  }
#undef STEP0A
#undef STEP0B
  hfin[(size_t)b*H + i]       = hA;
  hfin[((size_t)B + b)*H + i] = hB;
}

// layers 1,2 recurrence: dual-chain (fwd+bwd of one batch) per wave; pre
// streamed from HBM with depth-8 prefetch rings; compile-time layer/write_y.
template<int LAYER, int WRITEY>
__global__ __attribute__((amdgpu_flat_work_group_size(64,64)))
__attribute__((amdgpu_waves_per_eu(1,1)))
void k_rec(const float* __restrict__ pre,
           ushort_t* __restrict__ y,
           const float* __restrict__ w_hh,
           float* __restrict__ hfin)
{
  const int b = blockIdx.x;           // 0..127
  const int i = threadIdx.x;          // 0..63
  bool pick16=false, pick32=false;
  int cm[8];
  const int ba32 = (i^32)<<2, ba16 = (i^16)<<2;
  (void)ba32; (void)ba16;
  CALIB();
  float wA[64], wB[64];
  LOAD_W8(wA, w_hh + (size_t)(LAYER*2+0)*H*H);
  LOAD_W8(wB, w_hh + (size_t)(LAYER*2+1)*H*H);
  const float* pA = pre + ((size_t)b*S)*H + i;             // d=0 plane
  const float* pB = pre + ((size_t)M + (size_t)b*S)*H + i; // d=1 plane
  ushort_t* yA = y + (size_t)b*S*128 + i;
  ushort_t* yB = y + (size_t)b*S*128 + 64 + i;
  int tA = 0, tB = S-1;

  float plA[8], plB[8];
  #pragma unroll
  for (int k=0;k<8;++k){
    plA[k] = pA[(size_t)k*H];
    plB[k] = pB[(size_t)(S-1-k)*H];
  }
  float hA = 0.f, hB = 0.f;

#define STEPRA(r) do {                                                       \
    float acc = plA[r];                                                      \
    plA[r] = pA[(size_t)clamp_t(tA + 8)*H];                                  \
    BSTEPX(hA, wA, acc);                                                     \
    if (WRITEY) yA[(size_t)tA*128] = f2bf(hA);                               \
    tA += 1;                                                                 \
  } while(0)
#define STEPRB(r) do {                                                       \
    float acc = plB[r];                                                      \
    plB[r] = pB[(size_t)clamp_t(tB - 8)*H];                                  \
    BSTEPX(hB, wB, acc);                                                     \
    if (WRITEY) yB[(size_t)tB*128] = f2bf(hB);                               \
    tB -= 1;                                                                 \
  } while(0)

  for (int tq=0; tq<S; tq+=8){
    STEPRA(0); STEPRB(0);
    STEPRA(1); STEPRB(1);
    STEPRA(2); STEPRB(2);
    STEPRA(3); STEPRB(3);
    STEPRA(4); STEPRB(4);
    STEPRA(5); STEPRB(5);
    STEPRA(6); STEPRB(6);
    STEPRA(7); STEPRB(7);
  }
#undef STEPRA
#undef STEPRB
  hfin[(size_t)b*H + i]       = hA;
  hfin[((size_t)B + b)*H + i] = hB;
}

// layers 1,2 input projection: [M,128]@[128,128]^T. Yin is bf16, W is fp32.
#define KC 32
__global__ __launch_bounds__(256) void k_gemm(const ushort_t* __restrict__ Yin,
     const float* __restrict__ w_ih, const float* __restrict__ b_ih,
     const float* __restrict__ b_hh, float* __restrict__ pre, int layer)
{
  __shared__ float sY[KC][132];
  __shared__ float sW[KC][132];
  const int tid = threadIdx.x;
  const int m0 = blockIdx.x * 128;
  const int tn = (tid & 15) * 8;
  const int tm = (tid >> 4) * 8;
  float acc[8][8];
  #pragma unroll
  for (int a=0;a<8;++a)
    #pragma unroll
    for (int q=0;q<8;++q) acc[a][q]=0.f;
  const float* Wb = w_ih + (size_t)layer*2*H*E;
  for (int kc=0; kc<E; kc+=KC){
    #pragma unroll
    for (int r=0;r<2;++r){
      int idx = r*256 + tid;     // 0..511
      int ym = idx >> 2;         // 0..127
      int yk = (idx & 3)*8;      // 0,8,16,24
      const ushort_t* p = Yin + (size_t)(m0+ym)*E + kc + yk;
      ushort4 a = *(const ushort4*)p;
      ushort4 bq = *(const ushort4*)(p+4);
      sY[yk+0][ym]=bf2f(a.x);  sY[yk+1][ym]=bf2f(a.y);  sY[yk+2][ym]=bf2f(a.z);  sY[yk+3][ym]=bf2f(a.w);
      sY[yk+4][ym]=bf2f(bq.x); sY[yk+5][ym]=bf2f(bq.y); sY[yk+6][ym]=bf2f(bq.z); sY[yk+7][ym]=bf2f(bq.w);
    }
    #pragma unroll
    for (int r=0;r<4;++r){
      int idx = r*256 + tid;     // 0..1023
      int wn = idx >> 3;         // 0..127
      int wk = (idx & 7)*4;      // 0..28
      float4 v = *(const float4*)(Wb + (size_t)wn*E + kc + wk);
      sW[wk+0][wn]=v.x; sW[wk+1][wn]=v.y; sW[wk+2][wn]=v.z; sW[wk+3][wn]=v.w;
    }
    __syncthreads();
    #pragma unroll 4
    for (int k=0;k<KC;++k){
      float4 a0 = *(const float4*)&sY[k][tm];
      float4 a1 = *(const float4*)&sY[k][tm+4];
      float4 b0 = *(const float4*)&sW[k][tn];
      float4 b1 = *(const float4*)&sW[k][tn+4];
      float am[8]={a0.x,a0.y,a0.z,a0.w,a1.x,a1.y,a1.z,a1.w};
      float bn[8]={b0.x,b0.y,b0.z,b0.w,b1.x,b1.y,b1.z,b1.w};
      #pragma unroll
      for (int mi=0;mi<8;++mi)
        #pragma unroll
        for (int ni=0;ni<8;++ni)
          acc[mi][ni] = fmaf(am[mi], bn[ni], acc[mi][ni]);
    }
    __syncthreads();
  }
  const int d = tn >> 6;
  const int i0 = tn & 63;
  float bias[8];
  #pragma unroll
  for (int ni=0;ni<8;++ni)
    bias[ni] = b_ih[(size_t)(layer*2+d)*H + i0+ni] + b_hh[(size_t)(layer*2+d)*H + i0+ni];
  #pragma unroll
  for (int mi=0;mi<8;++mi){
    size_t off = ((size_t)d*M + (m0+tm+mi))*H + i0;
    float4 o0 = make_float4(acc[mi][0]+bias[0], acc[mi][1]+bias[1], acc[mi][2]+bias[2], acc[mi][3]+bias[3]);
    float4 o1 = make_float4(acc[mi][4]+bias[4], acc[mi][5]+bias[5], acc[mi][6]+bias[6], acc[mi][7]+bias[7]);
    *(float4*)(pre + off)     = o0;
    *(float4*)(pre + off + 4) = o1;
  }
}

// final FC head; also reduces the 16 pool partials. fp32 in/out.
__global__ __launch_bounds__(128) void k_fc(const float* __restrict__ psum, const float* __restrict__ pmax,
    const float* __restrict__ hfin, const float* __restrict__ fc1_w, const float* __restrict__ fc1_b,
    const float* __restrict__ fc2_w, const float* __restrict__ fc2_b, float* __restrict__ out)
{
  const int b = blockIdx.x, tid = threadIdx.x;
  __shared__ __align__(16) float comb[384];
  __shared__ float red[2];
  float s=0.f, m=-INFINITY;
  #pragma unroll
  for (int c=0;c<16;++c){
    s += psum[((size_t)b*16+c)*E + tid];
    m = fmaxf(m, pmax[((size_t)b*16+c)*E + tid]);
  }
  comb[128+tid] = s*(1.f/2048.f);
  comb[256+tid] = m;
  comb[tid] = (tid<64) ? hfin[(size_t)b*H + tid] : hfin[((size_t)B + b)*H + (tid-64)];
  __syncthreads();
  float acc = fc1_b[tid];
  const float4* wrow = (const float4*)(fc1_w + (size_t)tid*384);
  const float4* cb = (const float4*)comb;
  #pragma unroll 8
  for (int k=0;k<96;++k){
    float4 wv = wrow[k]; float4 cv = cb[k];
    acc = fmaf(wv.x,cv.x,acc); acc = fmaf(wv.y,cv.y,acc);
    acc = fmaf(wv.z,cv.z,acc); acc = fmaf(wv.w,cv.w,acc);
  }
  acc = fmaxf(acc, 0.f);
  float p = acc * fc2_w[tid];
  #pragma unroll
  for (int off=32; off>0; off>>=1) p += __shfl_down(p, off);
  if ((tid & 63)==0) red[tid>>6] = p;
  __syncthreads();
  if (tid==0) out[b] = red[0] + red[1] + fc2_b[0];
}

extern "C" void kernel_launch(void* const* d_in, const int* in_sizes, int n_in,
                              void* d_out, int out_size, void* d_ws, size_t ws_size,
                              hipStream_t stream)
{
  const int*   x     = (const int*)  d_in[0];
  const float* emb   = (const float*)d_in[1];
  const float* w_ih  = (const float*)d_in[2];
  const float* w_hh  = (const float*)d_in[3];
  const float* b_ih  = (const float*)d_in[4];
  const float* b_hh  = (const float*)d_in[5];
  const float* fc1_w = (const float*)d_in[6];
  const float* fc1_b = (const float*)d_in[7];
  const float* fc2_w = (const float*)d_in[8];
  const float* fc2_b = (const float*)d_in[9];
  float* out = (float*)d_out;

  // workspace: keep under ~204 MB
  char* ws = (char*)d_ws;
  float*    pre  = (float*)(ws);                                     // 2*M*H f32  = 134.2 MB (layers 1,2 only)
  ushort_t* y    = (ushort_t*)(ws + (size_t)2*M*H*4);                // M*128 bf16 =  67.1 MB
  float*    pe   = (float*)(ws + (size_t)2*M*H*4 + (size_t)M*128*2); // V*128 f32
  float*    psum = pe   + (size_t)V*128;                             // B*16*E f32
  float*    pmax = psum + (size_t)B*16*E;                            // B*16*E f32
  float*    hfin = pmax + (size_t)B*16*E;                            // 2*B*H f32

  k_pre_emb<<<V, 128, 0, stream>>>(emb, w_ih, b_ih, b_hh, pe);
  k_pool<<<dim3(B,16), 128, 0, stream>>>(x, emb, psum, pmax);
  k_rec0<<<B, 64, 0, stream>>>(x, pe, y, w_hh, hfin);
  k_gemm<<<M/128, 256, 0, stream>>>(y, w_ih, b_ih, b_hh, pre, 1);
  k_rec<1,1><<<B, 64, 0, stream>>>(pre, y, w_hh, hfin);
  k_gemm<<<M/128, 256, 0, stream>>>(y, w_ih, b_ih, b_hh, pre, 2);
  k_rec<2,0><<<B, 64, 0, stream>>>(pre, y, w_hh, hfin);
  k_fc<<<B, 128, 0, stream>>>(psum, pmax, hfin, fc1_w, fc1_b, fc2_w, fc2_b, out);
}

// Round 13
// 1387.765 us; speedup vs baseline: 2.0211x; 2.0211x over previous
//
#include <hip/hip_runtime.h>
#include <math.h>

#define B 128
#define S 2048
#define V 800
#define E 128
#define H 64
#define NL 3
#define M (B*S)

typedef unsigned short ushort_t;
typedef float f32x2 __attribute__((ext_vector_type(2)));

__device__ __forceinline__ float bf2f(unsigned short u){
  return __uint_as_float(((unsigned int)u) << 16);
}
__device__ __forceinline__ unsigned short f2bf(float f){
  unsigned int u = __float_as_uint(f);
  u += 0x7fff + ((u >> 16) & 1);          // round-to-nearest-even
  return (unsigned short)(u >> 16);
}
__device__ __forceinline__ float fast_tanh(float x){
  float e = __expf(2.f*x);
  return 1.f - 2.f*__builtin_amdgcn_rcpf(e+1.f);
}
__device__ __forceinline__ int clamp_t(int t){
  return t < 0 ? 0 : (t > S-1 ? S-1 : t);
}
// packed dual-f32 FMA: acc.lo += a.lo*b.lo; acc.hi += a.hi*b.hi
// (inline-asm form correctness-proven in round 2's passing kernel)
__device__ __forceinline__ void pk_fma(f32x2& acc, f32x2 a, f32x2 b){
  asm("v_pk_fma_f32 %0, %1, %2, %0" : "+v"(acc) : "v"(a), "v"(b));
}

// ---- all-VALU 8x8 butterfly matvec (R11-proven), pk_fma dot (R13) ---------
// Lane l owns h[l]. Rows per lane: l ^ G(k), G(k) = (k&3)|((k&4)<<2).
// Cols: preserve bits{0,1,4}; spread bits{2,3} (rot4 orbit) + bit5
// (permlane32 pair). Folds xor1/xor2 (quad_perm DPP) + xor16 (permlane16
// pair). Runtime calibration absorbs permlane pairing conventions.
// R13: dot packed as 32 v_pk_fma_f32 over row-pairs (2q,2q+1); accumulator
// pairs unpack to the SAME scalar fold sequence as R11 (float2 elems are
// separate VGPRs) -> no new cross-lane semantics, just half the fma issue.
#define DPP_XOR1 0xB1    // quad_perm [1,0,3,2]
#define DPP_XOR2 0x4E    // quad_perm [2,3,0,1]
#define DPP_ROR4  0x124  // row_ror:4
#define DPP_ROR8  0x128  // row_ror:8
#define DPP_ROR12 0x12C  // row_ror:12
#define DPPI(v, ctrl) __builtin_amdgcn_update_dpp(0, (v), (ctrl), 0xf, 0xf, false)
#define DPPF(v, ctrl) __int_as_float(DPPI(__float_as_int(v), (ctrl)))
__device__ __forceinline__ float bperm(int addr, float v){
  return __int_as_float(__builtin_amdgcn_ds_bpermute(addr, __float_as_int(v)));
}
__device__ __host__ __forceinline__ constexpr int Gmask(int k){
  return (k & 3) | ((k & 4) << 2);      // {0,1,2,3,16,17,18,19}
}

#if __has_builtin(__builtin_amdgcn_permlane32_swap)
#define HAVE_PL32 1
#else
#define HAVE_PL32 0
#endif
#if __has_builtin(__builtin_amdgcn_permlane16_swap)
#define HAVE_PL16 1
#else
#define HAVE_PL16 0
#endif

#if HAVE_PL32
#define XOR32F(x) ({ auto r_ = __builtin_amdgcn_permlane32_swap(__float_as_uint(x), __float_as_uint(x), false, false); \
                     __uint_as_float(pick32 ? r_[0] : r_[1]); })
#else
#define XOR32F(x) bperm(ba32, (x))
#endif
#if HAVE_PL16
#define XOR16F(x) ({ auto r_ = __builtin_amdgcn_permlane16_swap(__float_as_uint(x), __float_as_uint(x), false, false); \
                     __uint_as_float(pick16 ? r_[0] : r_[1]); })
#else
#define XOR16F(x) bperm(ba16, (x))
#endif

// Calibration: fills pick16, pick32, cm[8] (true source lane of gather op j).
#define CALIB() do {                                                         \
  int mk_ = i;                                                               \
  int g32m_;                                                                 \
  if (HAVE_PL32) {                                                           \
    auto r_ = __builtin_amdgcn_permlane32_swap((unsigned)mk_, (unsigned)mk_, false, false); \
    pick32 = ((int)r_[0] == (mk_ ^ 32));                                     \
    g32m_ = pick32 ? (int)r_[0] : (int)r_[1];                                \
  } else {                                                                   \
    g32m_ = mk_ ^ 32;                                                        \
  }                                                                          \
  if (HAVE_PL16) {                                                           \
    auto r_ = __builtin_amdgcn_permlane16_swap((unsigned)mk_, (unsigned)mk_, false, false); \
    pick16 = ((int)r_[0] == (mk_ ^ 16));                                     \
  }                                                                          \
  cm[0]=mk_;   cm[1]=DPPI(mk_,DPP_ROR4);                                     \
  cm[2]=DPPI(mk_,DPP_ROR8);  cm[3]=DPPI(mk_,DPP_ROR12);                      \
  cm[4]=g32m_; cm[5]=DPPI(g32m_,DPP_ROR4);                                   \
  cm[6]=DPPI(g32m_,DPP_ROR8); cm[7]=DPPI(g32m_,DPP_ROR12);                   \
} while(0)

// W-tile load: wp[q*8+j] = (W[i^G(2q)][cm j], W[i^G(2q+1)][cm j])
#define LOAD_W8P(wbase) do {                                                 \
  _Pragma("unroll")                                                          \
  for (int q=0;q<4;++q){                                                     \
    const float* r0_ = (wbase) + (size_t)(i ^ Gmask(2*q))*H;                 \
    const float* r1_ = (wbase) + (size_t)(i ^ Gmask(2*q+1))*H;               \
    _Pragma("unroll")                                                        \
    for (int j=0;j<8;++j)                                                    \
      wp[q*8+j] = (f32x2){ r0_[cm[j]], r1_[cm[j]] };                         \
  }                                                                          \
} while(0)

// one recurrence step: VALU gather (DPP rors + one permlane32 pair),
// 32 pk_fma tile dot (acc seeded in P0.x = row l), unpack, fold xor1,xor2
// (DPP) + xor16 (permlane16 pair, calibrated pick), tanh. Updates h.
#define BSTEP(acc_expr)                                                      \
  {                                                                          \
    float hv0_ = h;                                                          \
    float hv1_ = DPPF(h, DPP_ROR4);                                          \
    float hv2_ = DPPF(h, DPP_ROR8);                                          \
    float hv3_ = DPPF(h, DPP_ROR12);                                         \
    float g_  = XOR32F(h);                                                   \
    float hv4_ = g_;                                                         \
    float hv5_ = DPPF(g_, DPP_ROR4);                                         \
    float hv6_ = DPPF(g_, DPP_ROR8);                                         \
    float hv7_ = DPPF(g_, DPP_ROR12);                                        \
    f32x2 P0_ = {(acc_expr), 0.f};                                           \
    f32x2 P1_ = {0.f, 0.f}, P2_ = {0.f, 0.f}, P3_ = {0.f, 0.f};              \
    f32x2 hd_;                                                               \
    hd_=(f32x2){hv0_,hv0_}; pk_fma(P0_,wp[0],hd_); pk_fma(P1_,wp[8],hd_);    \
                            pk_fma(P2_,wp[16],hd_); pk_fma(P3_,wp[24],hd_);  \
    hd_=(f32x2){hv1_,hv1_}; pk_fma(P0_,wp[1],hd_); pk_fma(P1_,wp[9],hd_);    \
                            pk_fma(P2_,wp[17],hd_); pk_fma(P3_,wp[25],hd_);  \
    hd_=(f32x2){hv2_,hv2_}; pk_fma(P0_,wp[2],hd_); pk_fma(P1_,wp[10],hd_);   \
                            pk_fma(P2_,wp[18],hd_); pk_fma(P3_,wp[26],hd_);  \
    hd_=(f32x2){hv3_,hv3_}; pk_fma(P0_,wp[3],hd_); pk_fma(P1_,wp[11],hd_);   \
                            pk_fma(P2_,wp[19],hd_); pk_fma(P3_,wp[27],hd_);  \
    hd_=(f32x2){hv4_,hv4_}; pk_fma(P0_,wp[4],hd_); pk_fma(P1_,wp[12],hd_);   \
                            pk_fma(P2_,wp[20],hd_); pk_fma(P3_,wp[28],hd_);  \
    hd_=(f32x2){hv5_,hv5_}; pk_fma(P0_,wp[5],hd_); pk_fma(P1_,wp[13],hd_);   \
                            pk_fma(P2_,wp[21],hd_); pk_fma(P3_,wp[29],hd_);  \
    hd_=(f32x2){hv6_,hv6_}; pk_fma(P0_,wp[6],hd_); pk_fma(P1_,wp[14],hd_);   \
                            pk_fma(P2_,wp[22],hd_); pk_fma(P3_,wp[30],hd_);  \
    hd_=(f32x2){hv7_,hv7_}; pk_fma(P0_,wp[7],hd_); pk_fma(P1_,wp[15],hd_);   \
                            pk_fma(P2_,wp[23],hd_); pk_fma(P3_,wp[31],hd_);  \
    float p0_=P0_.x, p1_=P0_.y, p2_=P1_.x, p3_=P1_.y;                        \
    float p4_=P2_.x, p5_=P2_.y, p6_=P3_.x, p7_=P3_.y;                        \
    p0_ += DPPF(p1_, DPP_XOR1); p2_ += DPPF(p3_, DPP_XOR1);                  \
    p4_ += DPPF(p5_, DPP_XOR1); p6_ += DPPF(p7_, DPP_XOR1);                  \
    p0_ += DPPF(p2_, DPP_XOR2); p4_ += DPPF(p6_, DPP_XOR2);                  \
    p0_ += XOR16F(p4_);                                                      \
    h = fast_tanh(p0_);                                                      \
  }
// ---------------------------------------------------------------------------

// pre_emb[v][n] = emb[v]·w_ih[0,n,:] + b_ih[0,n] + b_hh[0,n],  n = d*64+i
__global__ __launch_bounds__(128) void k_pre_emb(const float* __restrict__ emb,
    const float* __restrict__ w_ih, const float* __restrict__ b_ih, const float* __restrict__ b_hh,
    float* __restrict__ pe)
{
  const int v = blockIdx.x;
  const int n = threadIdx.x;           // 0..127
  const float* er = emb + (size_t)v*E;
  const float* wr = w_ih + (size_t)n*E;   // layer 0 rows
  float acc = b_ih[n] + b_hh[n];
  #pragma unroll
  for (int e=0;e<E;e+=4){
    float4 ev = *(const float4*)(er+e);
    float4 wv = *(const float4*)(wr+e);
    acc = fmaf(ev.x, wv.x, acc);
    acc = fmaf(ev.y, wv.y, acc);
    acc = fmaf(ev.z, wv.z, acc);
    acc = fmaf(ev.w, wv.w, acc);
  }
  pe[(size_t)v*128 + n] = acc;
}

// partial mean/max pools over S-chunks
__global__ __launch_bounds__(128) void k_pool(const int* __restrict__ x, const float* __restrict__ emb,
      float* __restrict__ psum, float* __restrict__ pmax)
{
  const int b = blockIdx.x, c = blockIdx.y, e = threadIdx.x;
  const int* xb = x + (size_t)b*S + c*(S/16);
  float s=0.f, m=-INFINITY;
  for (int k=0;k<S/16;++k){
    int v = xb[k];
    float val = emb[(size_t)v*E + e];
    s += val; m = fmaxf(m,val);
  }
  psum[((size_t)b*16 + c)*E + e] = s;
  pmax[((size_t)b*16 + c)*E + e] = m;
}

// layer-0 recurrence, fused gather: pre[t] = pe[x[t]] (pe is 409 KB -> L2-hot).
// One wave per (d,b) chain; all-VALU butterfly dot with pk_fma.
__global__ __attribute__((amdgpu_flat_work_group_size(64,64)))
__attribute__((amdgpu_waves_per_eu(1,1)))
void k_rec0(const int* __restrict__ x,
            const float* __restrict__ pe,
            ushort_t* __restrict__ y,
            const float* __restrict__ w_hh,
            float* __restrict__ hfin)
{
  const int c = blockIdx.x;           // 0..255
  const int d = c >> 7;
  const int b = c & 127;
  const int i = threadIdx.x;          // 0..63
  bool pick16=false, pick32=false;
  int cm[8];
  const int ba32 = (i^32)<<2, ba16 = (i^16)<<2;
  (void)ba32; (void)ba16;
  CALIB();
  f32x2 wp[32];
  LOAD_W8P(w_hh + (size_t)d*H*H);     // layer 0
  const int* xb = x + (size_t)b*S;
  const float* peb = pe + d*H + i;    // + v*128 per step
  ushort_t* yb = y + (size_t)b*S*(2*H) + d*H + i;
  const int fwd = (d==0);
  const int dt = fwd ? 1 : -1;
  int t = fwd ? 0 : S-1;

  int vx[8];                          // x values for t .. t+7
  #pragma unroll
  for (int k=0;k<8;++k) vx[k] = xb[clamp_t(t + k*dt)];
  float pl[4];                        // pe rows for t .. t+3
  #pragma unroll
  for (int k=0;k<4;++k) pl[k] = peb[(size_t)vx[k]*128];
  float h = 0.f;

#define STEP0(r) do {                                                        \
    float acc = pl[(r)&3];                                                   \
    pl[(r)&3] = peb[(size_t)vx[((r)+4)&7]*128];  /* row for t+4 */           \
    vx[(r)&7] = xb[clamp_t(t + 8*dt)];           /* x for t+8  */            \
    BSTEP(acc);                                                              \
    yb[(size_t)t*(2*H)] = f2bf(h);                                           \
    t += dt;                                                                 \
  } while(0)

  for (int tq=0; tq<S; tq+=8){
    STEP0(0); STEP0(1); STEP0(2); STEP0(3);
    STEP0(4); STEP0(5); STEP0(6); STEP0(7);
  }
#undef STEP0
  hfin[((size_t)d*B + b)*H + i] = h;
}

// layers 1,2 recurrence: pre streamed from HBM (134 MB), depth-8 prefetch
// ring; all-VALU butterfly dot with pk_fma; compile-time layer/write_y.
template<int LAYER, int WRITEY>
__global__ __attribute__((amdgpu_flat_work_group_size(64,64)))
__attribute__((amdgpu_waves_per_eu(1,1)))
void k_rec(const float* __restrict__ pre,
           ushort_t* __restrict__ y,
           const float* __restrict__ w_hh,
           float* __restrict__ hfin)
{
  const int c = blockIdx.x;           // 0..255
  const int d = c >> 7;
  const int b = c & 127;
  const int i = threadIdx.x;          // 0..63
  bool pick16=false, pick32=false;
  int cm[8];
  const int ba32 = (i^32)<<2, ba16 = (i^16)<<2;
  (void)ba32; (void)ba16;
  CALIB();
  f32x2 wp[32];
  LOAD_W8P(w_hh + (size_t)(LAYER*2+d)*H*H);
  const float* pb = pre + ((size_t)d*M + (size_t)b*S)*H + i;
  ushort_t* yb = y + (size_t)b*S*(2*H) + d*H + i;
  const int fwd = (d==0);
  const int dt = fwd ? 1 : -1;
  int t = fwd ? 0 : S-1;

  float pl[8];                        // pre values for t .. t+7
  #pragma unroll
  for (int k=0;k<8;++k) pl[k] = pb[(size_t)clamp_t(t + k*dt)*H];
  float h = 0.f;

#define STEPR(r) do {                                                        \
    float acc = pl[r];                                                       \
    pl[r] = pb[(size_t)clamp_t(t + 8*dt)*H];     /* value for t+8 */         \
    BSTEP(acc);                                                              \
    if (WRITEY) yb[(size_t)t*(2*H)] = f2bf(h);                               \
    t += dt;                                                                 \
  } while(0)

  for (int tq=0; tq<S; tq+=8){
    STEPR(0); STEPR(1); STEPR(2); STEPR(3);
    STEPR(4); STEPR(5); STEPR(6); STEPR(7);
  }
#undef STEPR
  hfin[((size_t)d*B + b)*H + i] = h;
}

// layers 1,2 input projection: [M,128]@[128,128]^T. Yin is bf16, W is fp32.
#define KC 32
__global__ __launch_bounds__(256) void k_gemm(const ushort_t* __restrict__ Yin,
     const float* __restrict__ w_ih, const float* __restrict__ b_ih,
     const float* __restrict__ b_hh, float* __restrict__ pre, int layer)
{
  __shared__ float sY[KC][132];
  __shared__ float sW[KC][132];
  const int tid = threadIdx.x;
  const int m0 = blockIdx.x * 128;
  const int tn = (tid & 15) * 8;
  const int tm = (tid >> 4) * 8;
  float acc[8][8];
  #pragma unroll
  for (int a=0;a<8;++a)
    #pragma unroll
    for (int q=0;q<8;++q) acc[a][q]=0.f;
  const float* Wb = w_ih + (size_t)layer*2*H*E;
  for (int kc=0; kc<E; kc+=KC){
    #pragma unroll
    for (int r=0;r<2;++r){
      int idx = r*256 + tid;     // 0..511
      int ym = idx >> 2;         // 0..127
      int yk = (idx & 3)*8;      // 0,8,16,24
      const ushort_t* p = Yin + (size_t)(m0+ym)*E + kc + yk;
      ushort4 a = *(const ushort4*)p;
      ushort4 bq = *(const ushort4*)(p+4);
      sY[yk+0][ym]=bf2f(a.x);  sY[yk+1][ym]=bf2f(a.y);  sY[yk+2][ym]=bf2f(a.z);  sY[yk+3][ym]=bf2f(a.w);
      sY[yk+4][ym]=bf2f(bq.x); sY[yk+5][ym]=bf2f(bq.y); sY[yk+6][ym]=bf2f(bq.z); sY[yk+7][ym]=bf2f(bq.w);
    }
    #pragma unroll
    for (int r=0;r<4;++r){
      int idx = r*256 + tid;     // 0..1023
      int wn = idx >> 3;         // 0..127
      int wk = (idx & 7)*4;      // 0..28
      float4 v = *(const float4*)(Wb + (size_t)wn*E + kc + wk);
      sW[wk+0][wn]=v.x; sW[wk+1][wn]=v.y; sW[wk+2][wn]=v.z; sW[wk+3][wn]=v.w;
    }
    __syncthreads();
    #pragma unroll 4
    for (int k=0;k<KC;++k){
      float4 a0 = *(const float4*)&sY[k][tm];
      float4 a1 = *(const float4*)&sY[k][tm+4];
      float4 b0 = *(const float4*)&sW[k][tn];
      float4 b1 = *(const float4*)&sW[k][tn+4];
      float am[8]={a0.x,a0.y,a0.z,a0.w,a1.x,a1.y,a1.z,a1.w};
      float bn[8]={b0.x,b0.y,b0.z,b0.w,b1.x,b1.y,b1.z,b1.w};
      #pragma unroll
      for (int mi=0;mi<8;++mi)
        #pragma unroll
        for (int ni=0;ni<8;++ni)
          acc[mi][ni] = fmaf(am[mi], bn[ni], acc[mi][ni]);
    }
    __syncthreads();
  }
  const int d = tn >> 6;
  const int i0 = tn & 63;
  float bias[8];
  #pragma unroll
  for (int ni=0;ni<8;++ni)
    bias[ni] = b_ih[(size_t)(layer*2+d)*H + i0+ni] + b_hh[(size_t)(layer*2+d)*H + i0+ni];
  #pragma unroll
  for (int mi=0;mi<8;++mi){
    size_t off = ((size_t)d*M + (m0+tm+mi))*H + i0;
    float4 o0 = make_float4(acc[mi][0]+bias[0], acc[mi][1]+bias[1], acc[mi][2]+bias[2], acc[mi][3]+bias[3]);
    float4 o1 = make_float4(acc[mi][4]+bias[4], acc[mi][5]+bias[5], acc[mi][6]+bias[6], acc[mi][7]+bias[7]);
    *(float4*)(pre + off)     = o0;
    *(float4*)(pre + off + 4) = o1;
  }
}

// final FC head; also reduces the 16 pool partials. fp32 in/out.
__global__ __launch_bounds__(128) void k_fc(const float* __restrict__ psum, const float* __restrict__ pmax,
    const float* __restrict__ hfin, const float* __restrict__ fc1_w, const float* __restrict__ fc1_b,
    const float* __restrict__ fc2_w, const float* __restrict__ fc2_b, float* __restrict__ out)
{
  const int b = blockIdx.x, tid = threadIdx.x;
  __shared__ __align__(16) float comb[384];
  __shared__ float red[2];
  float s=0.f, m=-INFINITY;
  #pragma unroll
  for (int c=0;c<16;++c){
    s += psum[((size_t)b*16+c)*E + tid];
    m = fmaxf(m, pmax[((size_t)b*16+c)*E + tid]);
  }
  comb[128+tid] = s*(1.f/2048.f);
  comb[256+tid] = m;
  comb[tid] = (tid<64) ? hfin[(size_t)b*H + tid] : hfin[((size_t)B + b)*H + (tid-64)];
  __syncthreads();
  float acc = fc1_b[tid];
  const float4* wrow = (const float4*)(fc1_w + (size_t)tid*384);
  const float4* cb = (const float4*)comb;
  #pragma unroll 8
  for (int k=0;k<96;++k){
    float4 wv = wrow[k]; float4 cv = cb[k];
    acc = fmaf(wv.x,cv.x,acc); acc = fmaf(wv.y,cv.y,acc);
    acc = fmaf(wv.z,cv.z,acc); acc = fmaf(wv.w,cv.w,acc);
  }
  acc = fmaxf(acc, 0.f);
  float p = acc * fc2_w[tid];
  #pragma unroll
  for (int off=32; off>0; off>>=1) p += __shfl_down(p, off);
  if ((tid & 63)==0) red[tid>>6] = p;
  __syncthreads();
  if (tid==0) out[b] = red[0] + red[1] + fc2_b[0];
}

extern "C" void kernel_launch(void* const* d_in, const int* in_sizes, int n_in,
                              void* d_out, int out_size, void* d_ws, size_t ws_size,
                              hipStream_t stream)
{
  const int*   x     = (const int*)  d_in[0];
  const float* emb   = (const float*)d_in[1];
  const float* w_ih  = (const float*)d_in[2];
  const float* w_hh  = (const float*)d_in[3];
  const float* b_ih  = (const float*)d_in[4];
  const float* b_hh  = (const float*)d_in[5];
  const float* fc1_w = (const float*)d_in[6];
  const float* fc1_b = (const float*)d_in[7];
  const float* fc2_w = (const float*)d_in[8];
  const float* fc2_b = (const float*)d_in[9];
  float* out = (float*)d_out;

  // workspace: keep under ~204 MB
  char* ws = (char*)d_ws;
  float*    pre  = (float*)(ws);                                     // 2*M*H f32  = 134.2 MB (layers 1,2 only)
  ushort_t* y    = (ushort_t*)(ws + (size_t)2*M*H*4);                // M*128 bf16 =  67.1 MB
  float*    pe   = (float*)(ws + (size_t)2*M*H*4 + (size_t)M*128*2); // V*128 f32
  float*    psum = pe   + (size_t)V*128;                             // B*16*E f32
  float*    pmax = psum + (size_t)B*16*E;                            // B*16*E f32
  float*    hfin = pmax + (size_t)B*16*E;                            // 2*B*H f32

  k_pre_emb<<<V, 128, 0, stream>>>(emb, w_ih, b_ih, b_hh, pe);
  k_pool<<<dim3(B,16), 128, 0, stream>>>(x, emb, psum, pmax);
  k_rec0<<<256, 64, 0, stream>>>(x, pe, y, w_hh, hfin);
  k_gemm<<<M/128, 256, 0, stream>>>(y, w_ih, b_ih, b_hh, pre, 1);
  k_rec<1,1><<<256, 64, 0, stream>>>(pre, y, w_hh, hfin);
  k_gemm<<<M/128, 256, 0, stream>>>(y, w_ih, b_ih, b_hh, pre, 2);
  k_rec<2,0><<<256, 64, 0, stream>>>(pre, y, w_hh, hfin);
  k_fc<<<B, 128, 0, stream>>>(psum, pmax, hfin, fc1_w, fc1_b, fc2_w, fc2_b, out);
}